// Round 7
// baseline (1076.456 us; speedup 1.0000x reference)
//
#include <hip/hip_runtime.h>
#include <stdint.h>

#define GN 50000
#define GE 50000
#define GKK 16
#define DD 256
#define INDIM 240

typedef _Float16 f16;
typedef _Float16 half2t __attribute__((ext_vector_type(2)));
typedef _Float16 half4 __attribute__((ext_vector_type(4)));
typedef _Float16 half8 __attribute__((ext_vector_type(8)));
typedef float f32x4 __attribute__((ext_vector_type(4)));

__device__ inline float4 ld_h4(const f16* p) {
  half4 v = *(const half4*)p;
  return make_float4((float)v.x, (float)v.y, (float)v.z, (float)v.w);
}
__device__ inline void st_h4c(f16* p, float4 v) {
  half4 h;
  h.x = (f16)fminf(fmaxf(v.x, -60000.f), 60000.f);
  h.y = (f16)fminf(fmaxf(v.y, -60000.f), 60000.f);
  h.z = (f16)fminf(fmaxf(v.z, -60000.f), 60000.f);
  h.w = (f16)fminf(fmaxf(v.w, -60000.f), 60000.f);
  *(half4*)p = h;
}
__device__ inline f16 h_clamp(float v) {
  return (f16)fminf(fmaxf(v, -60000.f), 60000.f);
}

// ---------- scalar reductions ----------
__global__ __launch_bounds__(256) void k_reduce(const float* __restrict__ t, int n,
                                                unsigned int* maxbits, double* sum) {
  int i0 = blockIdx.x * blockDim.x + threadIdx.x;
  int stride = gridDim.x * blockDim.x;
  float m = 0.f; double s = 0.0;
  for (int i = i0; i < n; i += stride) { float v = t[i]; m = fmaxf(m, v); s += (double)v; }
  for (int o = 32; o; o >>= 1) { m = fmaxf(m, __shfl_xor(m, o)); s += __shfl_xor(s, o); }
  if ((threadIdx.x & 63) == 0) { atomicMax(maxbits, __float_as_uint(m)); atomicAdd(sum, s); }
}

// ---------- w[e], tnode ----------
__global__ __launch_bounds__(256) void k_w(const float* __restrict__ t,
                                           const unsigned int* maxbits, const double* sum,
                                           const float* __restrict__ Wt, const float* __restrict__ bt,
                                           float* __restrict__ w, float* __restrict__ tn) {
  int i = blockIdx.x * blockDim.x + threadIdx.x;
  float maxt = __uint_as_float(*maxbits);
  if (i < GE) w[i] = expf((t[i] - maxt) * (1.0f / 365.0f));
  if (blockIdx.x == 0 && threadIdx.x < 16) {
    float mean = (float)(*sum / (double)GE);
    tn[threadIdx.x] = mean * Wt[threadIdx.x] + bt[threadIdx.x];
  }
}

// ---------- CSR build ----------
__global__ __launch_bounds__(256) void k_count(const int* __restrict__ edges, int* __restrict__ cnt) {
  int i = blockIdx.x * 256 + threadIdx.x;
  if (i < GE * GKK) atomicAdd(&cnt[edges[i]], 1);
}

__global__ __launch_bounds__(256) void k_scan(const int* __restrict__ cnt, int* __restrict__ off) {
  __shared__ int part[256];
  int t = threadIdx.x;
  const int chunk = (GN + 255) / 256;
  int beg = t * chunk, end = beg + chunk; if (end > GN) end = GN; if (beg > GN) beg = GN;
  int s = 0;
  for (int i = beg; i < end; i++) s += cnt[i];
  part[t] = s; __syncthreads();
  for (int d = 1; d < 256; d <<= 1) {
    int v = (t >= d) ? part[t - d] : 0;
    __syncthreads();
    part[t] += v;
    __syncthreads();
  }
  int base = (t == 0) ? 0 : part[t - 1];
  for (int i = beg; i < end; i++) { off[i] = base; base += cnt[i]; }
  if (t == 255) off[GN] = base;
}

__global__ __launch_bounds__(256) void k_fill(const int* __restrict__ edges, const int* __restrict__ off,
                                              int* __restrict__ cur, int* __restrict__ csr) {
  int i = blockIdx.x * 256 + threadIdx.x;
  if (i < GE * GKK) {
    int n = edges[i];
    int p = atomicAdd(&cur[n], 1);
    csr[off[n] + p] = i >> 4;  // edge id (K=16)
  }
}

// ---------- dv_isqrt ----------
__global__ __launch_bounds__(256) void k_dv(const int* __restrict__ off, const int* __restrict__ csr,
                                            const float* __restrict__ w, float* __restrict__ dvis) {
  int n = blockIdx.x * 256 + threadIdx.x;
  if (n >= GN) return;
  float dv = 0.f;
  int e0 = off[n], e1 = off[n + 1];
  for (int j = e0; j < e1; j++) dv += w[csr[j]];
  dvis[n] = dv > 0.f ? 1.0f / sqrtf(fmaxf(dv, 1e-12f)) : 0.f;
}

// ---------- h0 = concat(X, tnode) -> f16 ----------
__global__ __launch_bounds__(256) void k_h0(const float* __restrict__ X, const float* __restrict__ tn,
                                            f16* __restrict__ h) {
  int wid = threadIdx.x >> 6, lane = threadIdx.x & 63;
  int n = blockIdx.x * 4 + wid;
  if (n >= GN) return;
  float4 v;
  if (lane < 60) v = *(const float4*)&X[(size_t)n * INDIM + (lane << 2)];
  else           v = *(const float4*)&tn[(lane - 60) << 2];
  st_h4c(&h[(size_t)n * DD + (lane << 2)], v);
}

// ---------- W[k][n] f32 -> BT[n][k] f16 ----------
__global__ __launch_bounds__(256) void k_trans_h(const float* __restrict__ W, f16* __restrict__ BT) {
  __shared__ float tile[32][33];
  int bx = blockIdx.x & 7;
  int by = blockIdx.x >> 3;
  int tx = threadIdx.x & 31, ty = threadIdx.x >> 5;
#pragma unroll
  for (int i = 0; i < 4; i++) {
    int k = by * 32 + ty + i * 8;
    tile[ty + i * 8][tx] = W[(size_t)k * DD + bx * 32 + tx];
  }
  __syncthreads();
#pragma unroll
  for (int i = 0; i < 4; i++) {
    int n = bx * 32 + ty + i * 8;
    BT[(size_t)n * DD + by * 32 + tx] = (f16)tile[tx][ty + i * 8];
  }
}

// ---------- MFMA GEMM (unchanged from R6) ----------
__global__ __launch_bounds__(256) void k_gemm_mfma(const f16* __restrict__ A,
                                                   const f16* __restrict__ BT,
                                                   const float* __restrict__ bias,
                                                   const float* __restrict__ dvis,
                                                   f16* __restrict__ out) {
  int t = threadIdx.x;
  int lane = t & 63;
  int wv = t >> 6;
  int row0 = blockIdx.x * 64;
  int col0 = wv * 64;
  int lr = lane & 15;
  int kg = lane >> 4;

  f32x4 acc[4][4];
#pragma unroll
  for (int m = 0; m < 4; m++)
#pragma unroll
    for (int n = 0; n < 4; n++) acc[m][n] = (f32x4)(0.f);

  for (int k0 = 0; k0 < DD; k0 += 32) {
    half8 a[4], b[4];
#pragma unroll
    for (int m = 0; m < 4; m++) {
      int r = row0 + m * 16 + lr;
      r = r < GN ? r : GN - 1;
      a[m] = *(const half8*)&A[(size_t)r * DD + k0 + kg * 8];
    }
#pragma unroll
    for (int n = 0; n < 4; n++) {
      int c = col0 + n * 16 + lr;
      b[n] = *(const half8*)&BT[(size_t)c * DD + k0 + kg * 8];
    }
#pragma unroll
    for (int m = 0; m < 4; m++)
#pragma unroll
      for (int n = 0; n < 4; n++)
        acc[m][n] = __builtin_amdgcn_mfma_f32_16x16x32_f16(a[m], b[n], acc[m][n], 0, 0, 0);
  }

#pragma unroll
  for (int m = 0; m < 4; m++) {
#pragma unroll
    for (int r = 0; r < 4; r++) {
      int row = row0 + m * 16 + kg * 4 + r;
      if (row < GN) {
        float s = dvis[row];
#pragma unroll
        for (int n = 0; n < 4; n++) {
          int c = col0 + n * 16 + lr;
          out[(size_t)row * DD + c] = h_clamp((acc[m][n][r] + bias[c]) * s);
        }
      }
    }
  }
}

// ---------- q[n] = h[n,:] . aw  (streamed row-dot) ----------
__global__ __launch_bounds__(256) void k_rowdot(const f16* __restrict__ h, const float* __restrict__ aw,
                                                float* __restrict__ q) {
  int wid = threadIdx.x >> 6, lane = threadIdx.x & 63;
  int n = blockIdx.x * 4 + wid;
  if (n >= GN) return;
  float4 v = ld_h4(&h[(size_t)n * DD + (lane << 2)]);
  float4 a4 = *(const float4*)&aw[lane << 2];
  float d = v.x * a4.x + v.y * a4.y + v.z * a4.z + v.w * a4.w;
  for (int o = 32; o; o >>= 1) d += __shfl_xor(d, o);
  if (lane == 0) q[n] = d;
}

// ---------- a[e] = sigmoid(mean_k q[edges[e,k]] + ab) ----------
__global__ __launch_bounds__(256) void k_att(const float* __restrict__ q, const int* __restrict__ edges,
                                             const float* __restrict__ ab, float* __restrict__ a) {
  int e = blockIdx.x * 256 + threadIdx.x;
  if (e >= GE) return;
  float s = 0.f;
#pragma unroll
  for (int k = 0; k < GKK; k++) s += q[edges[e * GKK + k]];
  a[e] = 1.0f / (1.0f + expf(-(s * (1.0f / GKK) + ab[0])));
}

// ---------- sliced edge gather: msg[e,slice] = (scale[e]/16) * sum_k xs[edges[e,k],slice] ----------
// slice = blockIdx.x & 7 (XCD-pinned, 32 dims = 64B); 16 lanes/edge, 16 edges/block.
__global__ __launch_bounds__(256) void k_edge_sliced(const f16* __restrict__ xs,
                                                     const int* __restrict__ edges,
                                                     const float* __restrict__ scale,
                                                     f16* __restrict__ msg) {
  int slice = blockIdx.x & 7;
  int chunk = blockIdx.x >> 3;
  int t = threadIdx.x;
  int g = t >> 4, l = t & 15;
  int e = chunk * 16 + g;
  if (e >= GE) return;
  int idx = edges[e * GKK + l];          // lane-parallel index load (64B/group)
  float sx = 0.f, sy = 0.f;
#pragma unroll
  for (int k = 0; k < GKK; k++) {
    int nd = __shfl(idx, (t & 48) + k);  // broadcast k-th member within group
    half2t hv = *(const half2t*)&xs[(size_t)nd * DD + slice * 32 + l * 2];
    sx += (float)hv.x; sy += (float)hv.y;
  }
  float f = scale[e] * (1.0f / GKK);
  half2t o;
  o.x = (f16)fminf(fmaxf(sx * f, -60000.f), 60000.f);
  o.y = (f16)fminf(fmaxf(sy * f, -60000.f), 60000.f);
  *(half2t*)&msg[(size_t)e * DD + slice * 32 + l * 2] = o;
}

// ---------- sliced node gather ----------
// MODE 0: out = dvis[n]*sum (f16);  MODE 1: leaky(sum/cnt) f16;  MODE 2: leaky(sum/cnt) f32
template <int MODE>
__global__ __launch_bounds__(256) void k_node_sliced(const f16* __restrict__ msg,
                                                     const int* __restrict__ off,
                                                     const int* __restrict__ csr,
                                                     const float* __restrict__ dvis,
                                                     const int* __restrict__ cnt,
                                                     f16* __restrict__ outh,
                                                     float* __restrict__ outf) {
  int slice = blockIdx.x & 7;
  int chunk = blockIdx.x >> 3;
  int t = threadIdx.x;
  int g = t >> 4, l = t & 15;
  int n = chunk * 16 + g;
  if (n >= GN) return;
  int e0 = off[n], e1 = off[n + 1];
  float sx = 0.f, sy = 0.f;
  for (int base = e0; base < e1; base += 16) {
    int m = e1 - base; if (m > 16) m = 16;
    int idx = (l < m) ? csr[base + l] : 0;
    for (int k = 0; k < m; k++) {
      int e = __shfl(idx, (t & 48) + k);
      half2t hv = *(const half2t*)&msg[(size_t)e * DD + slice * 32 + l * 2];
      sx += (float)hv.x; sy += (float)hv.y;
    }
  }
  float sc;
  if (MODE == 0) sc = dvis[n];
  else sc = 1.0f / fmaxf((float)cnt[n], 1.0f);
  sx *= sc; sy *= sc;
  if (MODE != 0) {
    sx = sx > 0.f ? sx : 0.2f * sx;
    sy = sy > 0.f ? sy : 0.2f * sy;
  }
  if (MODE == 2) {
    float2 o = make_float2(sx, sy);
    *(float2*)&outf[(size_t)n * DD + slice * 32 + l * 2] = o;
  } else {
    half2t o;
    o.x = (f16)fminf(fmaxf(sx, -60000.f), 60000.f);
    o.y = (f16)fminf(fmaxf(sy, -60000.f), 60000.f);
    *(half2t*)&outh[(size_t)n * DD + slice * 32 + l * 2] = o;
  }
}

extern "C" void kernel_launch(void* const* d_in, const int* in_sizes, int n_in,
                              void* d_out, int out_size, void* d_ws, size_t ws_size,
                              hipStream_t stream) {
  (void)in_sizes; (void)n_in; (void)out_size; (void)ws_size;
  const float* X    = (const float*)d_in[0];
  const int*   edges= (const int*)d_in[1];
  const float* vt   = (const float*)d_in[2];
  const float* Wt   = (const float*)d_in[3];
  const float* bt   = (const float*)d_in[4];
  const float* th1  = (const float*)d_in[5];
  const float* b1   = (const float*)d_in[6];
  const float* aw1  = (const float*)d_in[7];
  const float* ab1  = (const float*)d_in[8];
  const float* th2  = (const float*)d_in[9];
  const float* b2   = (const float*)d_in[10];
  const float* aw2  = (const float*)d_in[11];
  const float* ab2  = (const float*)d_in[12];
  float* outp = (float*)d_out;

  // ---- workspace layout (R6 base + aE appended; q reuses cur) ----
  char* p = (char*)d_ws;
  float* P0  = (float*)p; p += (size_t)GN * DD * 4;
  float* P1  = (float*)p; p += (size_t)GN * DD * 4;
  float* w   = (float*)p; p += (size_t)GE * 4;
  float* dvis= (float*)p; p += (size_t)GN * 4;
  float* tn  = (float*)p; p += 16 * 4;
  int* cnt   = (int*)p;   p += (size_t)GN * 4;
  int* off   = (int*)p;   p += (size_t)(GN + 1) * 4;
  int* cur   = (int*)p;   p += (size_t)GN * 4;
  int* csr   = (int*)p;   p += (size_t)GE * GKK * 4;
  p = (char*)(((uintptr_t)p + 15) & ~(uintptr_t)15);
  double* dsum = (double*)p;
  unsigned int* mbits = (unsigned int*)(p + 8);
  p += 16;
  f16* BT1 = (f16*)p; p += (size_t)DD * DD * 2;
  f16* BT2 = (f16*)p; p += (size_t)DD * DD * 2;
  float* aE = (float*)p; p += (size_t)GE * 4;      // per-edge attention scalar
  float* q  = (float*)cur;                         // cur dead after k_fill

  f16* SA = (f16*)P0;
  f16* SB = (f16*)((char*)P0 + (size_t)GN * DD * 2);
  f16* SC = (f16*)P1;
  f16* SD = (f16*)((char*)P1 + (size_t)GN * DD * 2);

  hipMemsetAsync(cnt, 0, (size_t)GN * 4, stream);
  hipMemsetAsync(cur, 0, (size_t)GN * 4, stream);
  hipMemsetAsync(dsum, 0, 16, stream);

  k_reduce<<<196, 256, 0, stream>>>(vt, GE, mbits, dsum);
  k_w<<<196, 256, 0, stream>>>(vt, mbits, dsum, Wt, bt, w, tn);
  k_count<<<3125, 256, 0, stream>>>(edges, cnt);
  k_scan<<<1, 256, 0, stream>>>(cnt, off);
  k_fill<<<3125, 256, 0, stream>>>(edges, off, cur, csr);
  k_dv<<<196, 256, 0, stream>>>(off, csr, w, dvis);
  k_trans_h<<<64, 256, 0, stream>>>(th1, BT1);
  k_trans_h<<<64, 256, 0, stream>>>(th2, BT2);
  k_h0<<<12500, 256, 0, stream>>>(X, tn, SA);

  const int GR = 25000;  // 3125 chunks x 8 slices

  // ---- layer 1 ----
  k_gemm_mfma<<<782, 256, 0, stream>>>(SA, BT1, b1, dvis, SC);              // h0(A) -> g1(C)
  k_edge_sliced<<<GR, 256, 0, stream>>>(SC, edges, w, SD);                  // g1 -> m1(D)
  k_node_sliced<0><<<GR, 256, 0, stream>>>(SD, off, csr, dvis, cnt, SB, nullptr); // m1 -> s1(B)
  k_rowdot<<<12500, 256, 0, stream>>>(SB, aw1, q);                          // s1 -> q
  k_att<<<196, 256, 0, stream>>>(q, edges, ab1, aE);                        // q -> aE
  k_edge_sliced<<<GR, 256, 0, stream>>>(SB, edges, aE, SC);                 // s1 -> m2(C; g1 dead)
  k_node_sliced<1><<<GR, 256, 0, stream>>>(SC, off, csr, dvis, cnt, SA, nullptr); // m2 -> L1(A; h0 dead)

  // ---- layer 2 ----
  k_gemm_mfma<<<782, 256, 0, stream>>>(SA, BT2, b2, dvis, SB);              // L1 -> g2(B; s1 dead)
  k_edge_sliced<<<GR, 256, 0, stream>>>(SB, edges, w, SC);                  // g2 -> m3(C; m2 dead)
  k_node_sliced<0><<<GR, 256, 0, stream>>>(SC, off, csr, dvis, cnt, SD, nullptr); // m3 -> s2(D; m1 dead)
  k_rowdot<<<12500, 256, 0, stream>>>(SD, aw2, q);                          // s2 -> q
  k_att<<<196, 256, 0, stream>>>(q, edges, ab2, aE);                        // q -> aE
  k_edge_sliced<<<GR, 256, 0, stream>>>(SD, edges, aE, SC);                 // s2 -> m4(C; m3 dead)
  k_node_sliced<2><<<GR, 256, 0, stream>>>(SC, off, csr, dvis, cnt, nullptr, outp); // m4 -> out (f32)
}

// Round 9
// 937.306 us; speedup vs baseline: 1.1485x; 1.1485x over previous
//
#include <hip/hip_runtime.h>
#include <stdint.h>

#define GN 50000
#define GE 50000
#define GKK 16
#define DD 256
#define INDIM 240

typedef _Float16 f16;
typedef _Float16 half4 __attribute__((ext_vector_type(4)));
typedef _Float16 half8 __attribute__((ext_vector_type(8)));
typedef float f32x4 __attribute__((ext_vector_type(4)));

__device__ inline float4 ld_h4(const f16* p) {
  half4 v = *(const half4*)p;
  return make_float4((float)v.x, (float)v.y, (float)v.z, (float)v.w);
}
// non-temporal clamped f16x4 store (gather outputs are streamed, read on other XCDs)
__device__ inline void st_h4c_nt(f16* p, float4 v) {
  half4 h;
  h.x = (f16)fminf(fmaxf(v.x, -60000.f), 60000.f);
  h.y = (f16)fminf(fmaxf(v.y, -60000.f), 60000.f);
  h.z = (f16)fminf(fmaxf(v.z, -60000.f), 60000.f);
  h.w = (f16)fminf(fmaxf(v.w, -60000.f), 60000.f);
  __builtin_nontemporal_store(h, (half4*)p);
}
__device__ inline f16 h_clamp(float v) {
  return (f16)fminf(fmaxf(v, -60000.f), 60000.f);
}

// ---------- scalar reductions ----------
__global__ __launch_bounds__(256) void k_reduce(const float* __restrict__ t, int n,
                                                unsigned int* maxbits, double* sum) {
  int i0 = blockIdx.x * blockDim.x + threadIdx.x;
  int stride = gridDim.x * blockDim.x;
  float m = 0.f; double s = 0.0;
  for (int i = i0; i < n; i += stride) { float v = t[i]; m = fmaxf(m, v); s += (double)v; }
  for (int o = 32; o; o >>= 1) { m = fmaxf(m, __shfl_xor(m, o)); s += __shfl_xor(s, o); }
  if ((threadIdx.x & 63) == 0) { atomicMax(maxbits, __float_as_uint(m)); atomicAdd(sum, s); }
}

// ---------- w[e], tnode ----------
__global__ __launch_bounds__(256) void k_w(const float* __restrict__ t,
                                           const unsigned int* maxbits, const double* sum,
                                           const float* __restrict__ Wt, const float* __restrict__ bt,
                                           float* __restrict__ w, float* __restrict__ tn) {
  int i = blockIdx.x * blockDim.x + threadIdx.x;
  float maxt = __uint_as_float(*maxbits);
  if (i < GE) w[i] = expf((t[i] - maxt) * (1.0f / 365.0f));
  if (blockIdx.x == 0 && threadIdx.x < 16) {
    float mean = (float)(*sum / (double)GE);
    tn[threadIdx.x] = mean * Wt[threadIdx.x] + bt[threadIdx.x];
  }
}

// ---------- CSR build ----------
__global__ __launch_bounds__(256) void k_count(const int* __restrict__ edges, int* __restrict__ cnt) {
  int i = blockIdx.x * 256 + threadIdx.x;
  if (i < GE * GKK) atomicAdd(&cnt[edges[i]], 1);
}

__global__ __launch_bounds__(256) void k_scan(const int* __restrict__ cnt, int* __restrict__ off) {
  __shared__ int part[256];
  int t = threadIdx.x;
  const int chunk = (GN + 255) / 256;
  int beg = t * chunk, end = beg + chunk; if (end > GN) end = GN; if (beg > GN) beg = GN;
  int s = 0;
  for (int i = beg; i < end; i++) s += cnt[i];
  part[t] = s; __syncthreads();
  for (int d = 1; d < 256; d <<= 1) {
    int v = (t >= d) ? part[t - d] : 0;
    __syncthreads();
    part[t] += v;
    __syncthreads();
  }
  int base = (t == 0) ? 0 : part[t - 1];
  for (int i = beg; i < end; i++) { off[i] = base; base += cnt[i]; }
  if (t == 255) off[GN] = base;
}

__global__ __launch_bounds__(256) void k_fill(const int* __restrict__ edges, const int* __restrict__ off,
                                              int* __restrict__ cur, int* __restrict__ csr) {
  int i = blockIdx.x * 256 + threadIdx.x;
  if (i < GE * GKK) {
    int n = edges[i];
    int p = atomicAdd(&cur[n], 1);
    csr[off[n] + p] = i >> 4;  // edge id (K=16)
  }
}

// ---------- dv_isqrt ----------
__global__ __launch_bounds__(256) void k_dv(const int* __restrict__ off, const int* __restrict__ csr,
                                            const float* __restrict__ w, float* __restrict__ dvis) {
  int n = blockIdx.x * 256 + threadIdx.x;
  if (n >= GN) return;
  float dv = 0.f;
  int e0 = off[n], e1 = off[n + 1];
  for (int j = e0; j < e1; j++) dv += w[csr[j]];
  dvis[n] = dv > 0.f ? 1.0f / sqrtf(fmaxf(dv, 1e-12f)) : 0.f;
}

// ---------- h0 = concat(X, tnode) -> f16 ----------
__global__ __launch_bounds__(256) void k_h0(const float* __restrict__ X, const float* __restrict__ tn,
                                            f16* __restrict__ h) {
  int wid = threadIdx.x >> 6, lane = threadIdx.x & 63;
  int n = blockIdx.x * 4 + wid;
  if (n >= GN) return;
  float4 v;
  if (lane < 60) v = *(const float4*)&X[(size_t)n * INDIM + (lane << 2)];
  else           v = *(const float4*)&tn[(lane - 60) << 2];
  st_h4c_nt(&h[(size_t)n * DD + (lane << 2)], v);
}

// ---------- W[k][n] f32 -> BT[n][k] f16 ----------
__global__ __launch_bounds__(256) void k_trans_h(const float* __restrict__ W, f16* __restrict__ BT) {
  __shared__ float tile[32][33];
  int bx = blockIdx.x & 7;
  int by = blockIdx.x >> 3;
  int tx = threadIdx.x & 31, ty = threadIdx.x >> 5;
#pragma unroll
  for (int i = 0; i < 4; i++) {
    int k = by * 32 + ty + i * 8;
    tile[ty + i * 8][tx] = W[(size_t)k * DD + bx * 32 + tx];
  }
  __syncthreads();
#pragma unroll
  for (int i = 0; i < 4; i++) {
    int n = bx * 32 + ty + i * 8;
    BT[(size_t)n * DD + by * 32 + tx] = (f16)tile[tx][ty + i * 8];
  }
}

// ---------- MFMA GEMM: out[r,:] = (A[r,:] @ W + bias) * dvis[r] ----------
// A loads non-temporal (each row read by exactly one block); BT cached (128 KB, all blocks).
__global__ __launch_bounds__(256) void k_gemm_mfma(const f16* __restrict__ A,
                                                   const f16* __restrict__ BT,
                                                   const float* __restrict__ bias,
                                                   const float* __restrict__ dvis,
                                                   f16* __restrict__ out) {
  int t = threadIdx.x;
  int lane = t & 63;
  int wv = t >> 6;
  int row0 = blockIdx.x * 64;
  int col0 = wv * 64;
  int lr = lane & 15;
  int kg = lane >> 4;

  f32x4 acc[4][4];
#pragma unroll
  for (int m = 0; m < 4; m++)
#pragma unroll
    for (int n = 0; n < 4; n++) acc[m][n] = (f32x4)(0.f);

  for (int k0 = 0; k0 < DD; k0 += 32) {
    half8 a[4], b[4];
#pragma unroll
    for (int m = 0; m < 4; m++) {
      int r = row0 + m * 16 + lr;
      r = r < GN ? r : GN - 1;
      a[m] = __builtin_nontemporal_load((const half8*)&A[(size_t)r * DD + k0 + kg * 8]);
    }
#pragma unroll
    for (int n = 0; n < 4; n++) {
      int c = col0 + n * 16 + lr;
      b[n] = *(const half8*)&BT[(size_t)c * DD + k0 + kg * 8];
    }
#pragma unroll
    for (int m = 0; m < 4; m++)
#pragma unroll
      for (int n = 0; n < 4; n++)
        acc[m][n] = __builtin_amdgcn_mfma_f32_16x16x32_f16(a[m], b[n], acc[m][n], 0, 0, 0);
  }

#pragma unroll
  for (int m = 0; m < 4; m++) {
#pragma unroll
    for (int r = 0; r < 4; r++) {
      int row = row0 + m * 16 + kg * 4 + r;
      if (row < GN) {
        float s = dvis[row];
#pragma unroll
        for (int n = 0; n < 4; n++) {
          int c = col0 + n * 16 + lr;
          f16 hv = h_clamp((acc[m][n][r] + bias[c]) * s);
          __builtin_nontemporal_store(hv, &out[(size_t)row * DD + c]);
        }
      }
    }
  }
}

// ---------- q[n] = h[n,:] . aw  (streamed row-dot) ----------
__global__ __launch_bounds__(256) void k_rowdot(const f16* __restrict__ h, const float* __restrict__ aw,
                                                float* __restrict__ q) {
  int wid = threadIdx.x >> 6, lane = threadIdx.x & 63;
  int n = blockIdx.x * 4 + wid;
  if (n >= GN) return;
  float4 v = ld_h4(&h[(size_t)n * DD + (lane << 2)]);
  float4 a4 = *(const float4*)&aw[lane << 2];
  float d = v.x * a4.x + v.y * a4.y + v.z * a4.z + v.w * a4.w;
  for (int o = 32; o; o >>= 1) d += __shfl_xor(d, o);
  if (lane == 0) q[n] = d;
}

// ---------- a[e] = sigmoid(mean_k q[edges[e,k]] + ab) ----------
__global__ __launch_bounds__(256) void k_att(const float* __restrict__ q, const int* __restrict__ edges,
                                             const float* __restrict__ ab, float* __restrict__ a) {
  int e = blockIdx.x * 256 + threadIdx.x;
  if (e >= GE) return;
  float s = 0.f;
#pragma unroll
  for (int k = 0; k < GKK; k++) s += q[edges[e * GKK + k]];
  a[e] = 1.0f / (1.0f + expf(-(s * (1.0f / GKK) + ab[0])));
}

// ---------- per-edge: msg[e] = scale[e]/16 * sum_k xs[edges[e,k]]  (full-row, NT out) ----------
__global__ __launch_bounds__(256) void k_edge_msg(const f16* __restrict__ xs, const int* __restrict__ edges,
                                                  const float* __restrict__ scale, f16* __restrict__ msg) {
  int wid = threadIdx.x >> 6, lane = threadIdx.x & 63;
  int e = blockIdx.x * 4 + wid;
  if (e >= GE) return;
  float4 s = make_float4(0.f, 0.f, 0.f, 0.f);
#pragma unroll
  for (int k = 0; k < GKK; k++) {
    int nd = edges[e * GKK + k];
    float4 v = ld_h4(&xs[(size_t)nd * DD + (lane << 2)]);
    s.x += v.x; s.y += v.y; s.z += v.z; s.w += v.w;
  }
  float f = scale[e] * (1.0f / GKK);
  s.x *= f; s.y *= f; s.z *= f; s.w *= f;
  st_h4c_nt(&msg[(size_t)e * DD + (lane << 2)], s);
}

// ---------- per-node: h[n] = dvis[n] * sum msg[e]  (NT out) ----------
__global__ __launch_bounds__(256) void k_node_smooth(const f16* __restrict__ msg, const int* __restrict__ off,
                                                     const int* __restrict__ csr, const float* __restrict__ dvis,
                                                     f16* __restrict__ out) {
  int wid = threadIdx.x >> 6, lane = threadIdx.x & 63;
  int n = blockIdx.x * 4 + wid;
  if (n >= GN) return;
  int e0 = off[n], e1 = off[n + 1];
  float4 s = make_float4(0.f, 0.f, 0.f, 0.f);
  for (int j = e0; j < e1; j++) {
    int e = csr[j];
    float4 v = ld_h4(&msg[(size_t)e * DD + (lane << 2)]);
    s.x += v.x; s.y += v.y; s.z += v.z; s.w += v.w;
  }
  float sc = dvis[n];
  s.x *= sc; s.y *= sc; s.z *= sc; s.w *= sc;
  st_h4c_nt(&out[(size_t)n * DD + (lane << 2)], s);
}

// ---------- per-node attention aggregate, f16 out (NT) ----------
__global__ __launch_bounds__(256) void k_node_att_h(const f16* __restrict__ msg, const int* __restrict__ off,
                                                    const int* __restrict__ csr, const int* __restrict__ cnt,
                                                    f16* __restrict__ out) {
  int wid = threadIdx.x >> 6, lane = threadIdx.x & 63;
  int n = blockIdx.x * 4 + wid;
  if (n >= GN) return;
  int e0 = off[n], e1 = off[n + 1];
  float4 s = make_float4(0.f, 0.f, 0.f, 0.f);
  for (int j = e0; j < e1; j++) {
    int e = csr[j];
    float4 v = ld_h4(&msg[(size_t)e * DD + (lane << 2)]);
    s.x += v.x; s.y += v.y; s.z += v.z; s.w += v.w;
  }
  float inv = 1.0f / fmaxf((float)cnt[n], 1.0f);
  s.x *= inv; s.y *= inv; s.z *= inv; s.w *= inv;
  float4 o;
  o.x = s.x > 0.f ? s.x : 0.2f * s.x;
  o.y = s.y > 0.f ? s.y : 0.2f * s.y;
  o.z = s.z > 0.f ? s.z : 0.2f * s.z;
  o.w = s.w > 0.f ? s.w : 0.2f * s.w;
  st_h4c_nt(&out[(size_t)n * DD + (lane << 2)], o);
}

// ---------- per-node attention aggregate, f32 out (final, NT) ----------
__global__ __launch_bounds__(256) void k_node_att_f(const f16* __restrict__ msg, const int* __restrict__ off,
                                                    const int* __restrict__ csr, const int* __restrict__ cnt,
                                                    float* __restrict__ out) {
  int wid = threadIdx.x >> 6, lane = threadIdx.x & 63;
  int n = blockIdx.x * 4 + wid;
  if (n >= GN) return;
  int e0 = off[n], e1 = off[n + 1];
  float4 s = make_float4(0.f, 0.f, 0.f, 0.f);
  for (int j = e0; j < e1; j++) {
    int e = csr[j];
    float4 v = ld_h4(&msg[(size_t)e * DD + (lane << 2)]);
    s.x += v.x; s.y += v.y; s.z += v.z; s.w += v.w;
  }
  float inv = 1.0f / fmaxf((float)cnt[n], 1.0f);
  s.x *= inv; s.y *= inv; s.z *= inv; s.w *= inv;
  f32x4 o;
  o.x = s.x > 0.f ? s.x : 0.2f * s.x;
  o.y = s.y > 0.f ? s.y : 0.2f * s.y;
  o.z = s.z > 0.f ? s.z : 0.2f * s.z;
  o.w = s.w > 0.f ? s.w : 0.2f * s.w;
  __builtin_nontemporal_store(o, (f32x4*)&out[(size_t)n * DD + (lane << 2)]);
}

extern "C" void kernel_launch(void* const* d_in, const int* in_sizes, int n_in,
                              void* d_out, int out_size, void* d_ws, size_t ws_size,
                              hipStream_t stream) {
  (void)in_sizes; (void)n_in; (void)out_size; (void)ws_size;
  const float* X    = (const float*)d_in[0];
  const int*   edges= (const int*)d_in[1];
  const float* vt   = (const float*)d_in[2];
  const float* Wt   = (const float*)d_in[3];
  const float* bt   = (const float*)d_in[4];
  const float* th1  = (const float*)d_in[5];
  const float* b1   = (const float*)d_in[6];
  const float* aw1  = (const float*)d_in[7];
  const float* ab1  = (const float*)d_in[8];
  const float* th2  = (const float*)d_in[9];
  const float* b2   = (const float*)d_in[10];
  const float* aw2  = (const float*)d_in[11];
  const float* ab2  = (const float*)d_in[12];
  float* outp = (float*)d_out;

  // ---- workspace layout (R6 base + aE; q reuses cur) ----
  char* p = (char*)d_ws;
  float* P0  = (float*)p; p += (size_t)GN * DD * 4;
  float* P1  = (float*)p; p += (size_t)GN * DD * 4;
  float* w   = (float*)p; p += (size_t)GE * 4;
  float* dvis= (float*)p; p += (size_t)GN * 4;
  float* tn  = (float*)p; p += 16 * 4;
  int* cnt   = (int*)p;   p += (size_t)GN * 4;
  int* off   = (int*)p;   p += (size_t)(GN + 1) * 4;
  int* cur   = (int*)p;   p += (size_t)GN * 4;
  int* csr   = (int*)p;   p += (size_t)GE * GKK * 4;
  p = (char*)(((uintptr_t)p + 15) & ~(uintptr_t)15);
  double* dsum = (double*)p;
  unsigned int* mbits = (unsigned int*)(p + 8);
  p += 16;
  f16* BT1 = (f16*)p; p += (size_t)DD * DD * 2;
  f16* BT2 = (f16*)p; p += (size_t)DD * DD * 2;
  float* aE = (float*)p; p += (size_t)GE * 4;
  float* q  = (float*)cur;  // cur dead after k_fill

  f16* SA = (f16*)P0;
  f16* SB = (f16*)((char*)P0 + (size_t)GN * DD * 2);
  f16* SC = (f16*)P1;
  f16* SD = (f16*)((char*)P1 + (size_t)GN * DD * 2);

  hipMemsetAsync(cnt, 0, (size_t)GN * 4, stream);
  hipMemsetAsync(cur, 0, (size_t)GN * 4, stream);
  hipMemsetAsync(dsum, 0, 16, stream);

  k_reduce<<<196, 256, 0, stream>>>(vt, GE, mbits, dsum);
  k_w<<<196, 256, 0, stream>>>(vt, mbits, dsum, Wt, bt, w, tn);
  k_count<<<3125, 256, 0, stream>>>(edges, cnt);
  k_scan<<<1, 256, 0, stream>>>(cnt, off);
  k_fill<<<3125, 256, 0, stream>>>(edges, off, cur, csr);
  k_dv<<<196, 256, 0, stream>>>(off, csr, w, dvis);
  k_trans_h<<<64, 256, 0, stream>>>(th1, BT1);
  k_trans_h<<<64, 256, 0, stream>>>(th2, BT2);
  k_h0<<<12500, 256, 0, stream>>>(X, tn, SA);

  // ---- layer 1 ----
  k_gemm_mfma<<<782, 256, 0, stream>>>(SA, BT1, b1, dvis, SC);          // h0(A) -> g1(C)
  k_edge_msg<<<12500, 256, 0, stream>>>(SC, edges, w, SD);              // g1 -> m1(D)
  k_node_smooth<<<12500, 256, 0, stream>>>(SD, off, csr, dvis, SB);     // m1 -> s1(B)
  k_rowdot<<<12500, 256, 0, stream>>>(SB, aw1, q);                      // s1 -> q
  k_att<<<196, 256, 0, stream>>>(q, edges, ab1, aE);                    // q -> aE
  k_edge_msg<<<12500, 256, 0, stream>>>(SB, edges, aE, SC);             // s1 -> m2(C; g1 dead)
  k_node_att_h<<<12500, 256, 0, stream>>>(SC, off, csr, cnt, SA);       // m2 -> L1(A; h0 dead)

  // ---- layer 2 ----
  k_gemm_mfma<<<782, 256, 0, stream>>>(SA, BT2, b2, dvis, SB);          // L1 -> g2(B; s1 dead)
  k_edge_msg<<<12500, 256, 0, stream>>>(SB, edges, w, SC);              // g2 -> m3(C; m2 dead)
  k_node_smooth<<<12500, 256, 0, stream>>>(SC, off, csr, dvis, SD);     // m3 -> s2(D; m1 dead)
  k_rowdot<<<12500, 256, 0, stream>>>(SD, aw2, q);                      // s2 -> q
  k_att<<<196, 256, 0, stream>>>(q, edges, ab2, aE);                    // q -> aE
  k_edge_msg<<<12500, 256, 0, stream>>>(SD, edges, aE, SC);             // s2 -> m4(C; m3 dead)
  k_node_att_f<<<12500, 256, 0, stream>>>(SC, off, csr, cnt, outp);     // m4 -> out (f32)
}

// Round 10
// 879.534 us; speedup vs baseline: 1.2239x; 1.0657x over previous
//
#include <hip/hip_runtime.h>
#include <stdint.h>

#define GN 50000
#define GE 50000
#define GKK 16
#define DD 256
#define INDIM 240

typedef _Float16 f16;
typedef _Float16 half4 __attribute__((ext_vector_type(4)));
typedef _Float16 half8 __attribute__((ext_vector_type(8)));
typedef float f32x4 __attribute__((ext_vector_type(4)));

__device__ inline float4 ld_h4(const f16* p) {
  half4 v = *(const half4*)p;
  return make_float4((float)v.x, (float)v.y, (float)v.z, (float)v.w);
}
__device__ inline void st_h4c(f16* p, float4 v) {
  half4 h;
  h.x = (f16)fminf(fmaxf(v.x, -60000.f), 60000.f);
  h.y = (f16)fminf(fmaxf(v.y, -60000.f), 60000.f);
  h.z = (f16)fminf(fmaxf(v.z, -60000.f), 60000.f);
  h.w = (f16)fminf(fmaxf(v.w, -60000.f), 60000.f);
  *(half4*)p = h;
}
__device__ inline f16 h_clamp(float v) {
  return (f16)fminf(fmaxf(v, -60000.f), 60000.f);
}

// ---------- scalar reductions ----------
__global__ __launch_bounds__(256) void k_reduce(const float* __restrict__ t, int n,
                                                unsigned int* maxbits, double* sum) {
  int i0 = blockIdx.x * blockDim.x + threadIdx.x;
  int stride = gridDim.x * blockDim.x;
  float m = 0.f; double s = 0.0;
  for (int i = i0; i < n; i += stride) { float v = t[i]; m = fmaxf(m, v); s += (double)v; }
  for (int o = 32; o; o >>= 1) { m = fmaxf(m, __shfl_xor(m, o)); s += __shfl_xor(s, o); }
  if ((threadIdx.x & 63) == 0) { atomicMax(maxbits, __float_as_uint(m)); atomicAdd(sum, s); }
}

// ---------- w[e], tnode ----------
__global__ __launch_bounds__(256) void k_w(const float* __restrict__ t,
                                           const unsigned int* maxbits, const double* sum,
                                           const float* __restrict__ Wt, const float* __restrict__ bt,
                                           float* __restrict__ w, float* __restrict__ tn) {
  int i = blockIdx.x * blockDim.x + threadIdx.x;
  float maxt = __uint_as_float(*maxbits);
  if (i < GE) w[i] = expf((t[i] - maxt) * (1.0f / 365.0f));
  if (blockIdx.x == 0 && threadIdx.x < 16) {
    float mean = (float)(*sum / (double)GE);
    tn[threadIdx.x] = mean * Wt[threadIdx.x] + bt[threadIdx.x];
  }
}

// ---------- CSR build ----------
__global__ __launch_bounds__(256) void k_count(const int* __restrict__ edges, int* __restrict__ cnt) {
  int i = blockIdx.x * 256 + threadIdx.x;
  if (i < GE * GKK) atomicAdd(&cnt[edges[i]], 1);
}

__global__ __launch_bounds__(256) void k_scan(const int* __restrict__ cnt, int* __restrict__ off) {
  __shared__ int part[256];
  int t = threadIdx.x;
  const int chunk = (GN + 255) / 256;
  int beg = t * chunk, end = beg + chunk; if (end > GN) end = GN; if (beg > GN) beg = GN;
  int s = 0;
  for (int i = beg; i < end; i++) s += cnt[i];
  part[t] = s; __syncthreads();
  for (int d = 1; d < 256; d <<= 1) {
    int v = (t >= d) ? part[t - d] : 0;
    __syncthreads();
    part[t] += v;
    __syncthreads();
  }
  int base = (t == 0) ? 0 : part[t - 1];
  for (int i = beg; i < end; i++) { off[i] = base; base += cnt[i]; }
  if (t == 255) off[GN] = base;
}

__global__ __launch_bounds__(256) void k_fill(const int* __restrict__ edges, const int* __restrict__ off,
                                              int* __restrict__ cur, int* __restrict__ csr) {
  int i = blockIdx.x * 256 + threadIdx.x;
  if (i < GE * GKK) {
    int n = edges[i];
    int p = atomicAdd(&cur[n], 1);
    csr[off[n] + p] = i >> 4;  // edge id (K=16)
  }
}

// ---------- dv_isqrt ----------
__global__ __launch_bounds__(256) void k_dv(const int* __restrict__ off, const int* __restrict__ csr,
                                            const float* __restrict__ w, float* __restrict__ dvis) {
  int n = blockIdx.x * 256 + threadIdx.x;
  if (n >= GN) return;
  float dv = 0.f;
  int e0 = off[n], e1 = off[n + 1];
  for (int j = e0; j < e1; j++) dv += w[csr[j]];
  dvis[n] = dv > 0.f ? 1.0f / sqrtf(fmaxf(dv, 1e-12f)) : 0.f;
}

// ---------- h0 = concat(X, tnode) -> f16 ----------
__global__ __launch_bounds__(256) void k_h0(const float* __restrict__ X, const float* __restrict__ tn,
                                            f16* __restrict__ h) {
  int wid = threadIdx.x >> 6, lane = threadIdx.x & 63;
  int n = blockIdx.x * 4 + wid;
  if (n >= GN) return;
  float4 v;
  if (lane < 60) v = *(const float4*)&X[(size_t)n * INDIM + (lane << 2)];
  else           v = *(const float4*)&tn[(lane - 60) << 2];
  st_h4c(&h[(size_t)n * DD + (lane << 2)], v);
}

// ---------- W[k][n] f32 -> BT[n][k] f16 ----------
__global__ __launch_bounds__(256) void k_trans_h(const float* __restrict__ W, f16* __restrict__ BT) {
  __shared__ float tile[32][33];
  int bx = blockIdx.x & 7;
  int by = blockIdx.x >> 3;
  int tx = threadIdx.x & 31, ty = threadIdx.x >> 5;
#pragma unroll
  for (int i = 0; i < 4; i++) {
    int k = by * 32 + ty + i * 8;
    tile[ty + i * 8][tx] = W[(size_t)k * DD + bx * 32 + tx];
  }
  __syncthreads();
#pragma unroll
  for (int i = 0; i < 4; i++) {
    int n = bx * 32 + ty + i * 8;
    BT[(size_t)n * DD + by * 32 + tx] = (f16)tile[tx][ty + i * 8];
  }
}

// ---------- MFMA GEMM (R6 version, plain loads/stores) ----------
__global__ __launch_bounds__(256) void k_gemm_mfma(const f16* __restrict__ A,
                                                   const f16* __restrict__ BT,
                                                   const float* __restrict__ bias,
                                                   const float* __restrict__ dvis,
                                                   f16* __restrict__ out) {
  int t = threadIdx.x;
  int lane = t & 63;
  int wv = t >> 6;
  int row0 = blockIdx.x * 64;
  int col0 = wv * 64;
  int lr = lane & 15;
  int kg = lane >> 4;

  f32x4 acc[4][4];
#pragma unroll
  for (int m = 0; m < 4; m++)
#pragma unroll
    for (int n = 0; n < 4; n++) acc[m][n] = (f32x4)(0.f);

  for (int k0 = 0; k0 < DD; k0 += 32) {
    half8 a[4], b[4];
#pragma unroll
    for (int m = 0; m < 4; m++) {
      int r = row0 + m * 16 + lr;
      r = r < GN ? r : GN - 1;
      a[m] = *(const half8*)&A[(size_t)r * DD + k0 + kg * 8];
    }
#pragma unroll
    for (int n = 0; n < 4; n++) {
      int c = col0 + n * 16 + lr;
      b[n] = *(const half8*)&BT[(size_t)c * DD + k0 + kg * 8];
    }
#pragma unroll
    for (int m = 0; m < 4; m++)
#pragma unroll
      for (int n = 0; n < 4; n++)
        acc[m][n] = __builtin_amdgcn_mfma_f32_16x16x32_f16(a[m], b[n], acc[m][n], 0, 0, 0);
  }

#pragma unroll
  for (int m = 0; m < 4; m++) {
#pragma unroll
    for (int r = 0; r < 4; r++) {
      int row = row0 + m * 16 + kg * 4 + r;
      if (row < GN) {
        float s = dvis[row];
#pragma unroll
        for (int n = 0; n < 4; n++) {
          int c = col0 + n * 16 + lr;
          out[(size_t)row * DD + c] = h_clamp((acc[m][n][r] + bias[c]) * s);
        }
      }
    }
  }
}

// ---------- a[e] = sigmoid(mean_k q[edges[e,k]] + ab) ----------
__global__ __launch_bounds__(256) void k_att(const float* __restrict__ q, const int* __restrict__ edges,
                                             const float* __restrict__ ab, float* __restrict__ a) {
  int e = blockIdx.x * 256 + threadIdx.x;
  if (e >= GE) return;
  float s = 0.f;
#pragma unroll
  for (int k = 0; k < GKK; k++) s += q[edges[e * GKK + k]];
  a[e] = 1.0f / (1.0f + expf(-(s * (1.0f / GKK) + ab[0])));
}

// ---------- per-edge: msg[e] = scale[e]/16 * sum_k xs[edges[e,k]] ----------
__global__ __launch_bounds__(256) void k_edge_msg(const f16* __restrict__ xs, const int* __restrict__ edges,
                                                  const float* __restrict__ scale, f16* __restrict__ msg) {
  int wid = threadIdx.x >> 6, lane = threadIdx.x & 63;
  int e = blockIdx.x * 4 + wid;
  if (e >= GE) return;
  float4 s = make_float4(0.f, 0.f, 0.f, 0.f);
#pragma unroll
  for (int k = 0; k < GKK; k++) {
    int nd = edges[e * GKK + k];
    float4 v = ld_h4(&xs[(size_t)nd * DD + (lane << 2)]);
    s.x += v.x; s.y += v.y; s.z += v.z; s.w += v.w;
  }
  float f = scale[e] * (1.0f / GKK);
  s.x *= f; s.y *= f; s.z *= f; s.w *= f;
  st_h4c(&msg[(size_t)e * DD + (lane << 2)], s);
}

// ---------- per-node smooth + fused rowdot: s1 = dvis*sum msg; q[n] = s1 . aw ----------
__global__ __launch_bounds__(256) void k_node_smooth_q(const f16* __restrict__ msg, const int* __restrict__ off,
                                                       const int* __restrict__ csr, const float* __restrict__ dvis,
                                                       const float* __restrict__ aw,
                                                       f16* __restrict__ out, float* __restrict__ q) {
  int wid = threadIdx.x >> 6, lane = threadIdx.x & 63;
  int n = blockIdx.x * 4 + wid;
  if (n >= GN) return;
  int e0 = off[n], e1 = off[n + 1];
  float4 s = make_float4(0.f, 0.f, 0.f, 0.f);
  for (int j = e0; j < e1; j++) {
    int e = csr[j];
    float4 v = ld_h4(&msg[(size_t)e * DD + (lane << 2)]);
    s.x += v.x; s.y += v.y; s.z += v.z; s.w += v.w;
  }
  float sc = dvis[n];
  s.x *= sc; s.y *= sc; s.z *= sc; s.w *= sc;
  st_h4c(&out[(size_t)n * DD + (lane << 2)], s);
  // fused rowdot (s is in registers; VALU is idle)
  float4 a4 = *(const float4*)&aw[lane << 2];
  float d = s.x * a4.x + s.y * a4.y + s.z * a4.z + s.w * a4.w;
  for (int o = 32; o; o >>= 1) d += __shfl_xor(d, o);
  if (lane == 0) q[n] = d;
}

// ---------- per-node attention aggregate, f16 out ----------
__global__ __launch_bounds__(256) void k_node_att_h(const f16* __restrict__ msg, const int* __restrict__ off,
                                                    const int* __restrict__ csr, const int* __restrict__ cnt,
                                                    f16* __restrict__ out) {
  int wid = threadIdx.x >> 6, lane = threadIdx.x & 63;
  int n = blockIdx.x * 4 + wid;
  if (n >= GN) return;
  int e0 = off[n], e1 = off[n + 1];
  float4 s = make_float4(0.f, 0.f, 0.f, 0.f);
  for (int j = e0; j < e1; j++) {
    int e = csr[j];
    float4 v = ld_h4(&msg[(size_t)e * DD + (lane << 2)]);
    s.x += v.x; s.y += v.y; s.z += v.z; s.w += v.w;
  }
  float inv = 1.0f / fmaxf((float)cnt[n], 1.0f);
  s.x *= inv; s.y *= inv; s.z *= inv; s.w *= inv;
  float4 o;
  o.x = s.x > 0.f ? s.x : 0.2f * s.x;
  o.y = s.y > 0.f ? s.y : 0.2f * s.y;
  o.z = s.z > 0.f ? s.z : 0.2f * s.z;
  o.w = s.w > 0.f ? s.w : 0.2f * s.w;
  st_h4c(&out[(size_t)n * DD + (lane << 2)], o);
}

// ---------- per-node attention aggregate, f32 out (final) ----------
__global__ __launch_bounds__(256) void k_node_att_f(const f16* __restrict__ msg, const int* __restrict__ off,
                                                    const int* __restrict__ csr, const int* __restrict__ cnt,
                                                    float* __restrict__ out) {
  int wid = threadIdx.x >> 6, lane = threadIdx.x & 63;
  int n = blockIdx.x * 4 + wid;
  if (n >= GN) return;
  int e0 = off[n], e1 = off[n + 1];
  float4 s = make_float4(0.f, 0.f, 0.f, 0.f);
  for (int j = e0; j < e1; j++) {
    int e = csr[j];
    float4 v = ld_h4(&msg[(size_t)e * DD + (lane << 2)]);
    s.x += v.x; s.y += v.y; s.z += v.z; s.w += v.w;
  }
  float inv = 1.0f / fmaxf((float)cnt[n], 1.0f);
  s.x *= inv; s.y *= inv; s.z *= inv; s.w *= inv;
  float4 o;
  o.x = s.x > 0.f ? s.x : 0.2f * s.x;
  o.y = s.y > 0.f ? s.y : 0.2f * s.y;
  o.z = s.z > 0.f ? s.z : 0.2f * s.z;
  o.w = s.w > 0.f ? s.w : 0.2f * s.w;
  *(float4*)&out[(size_t)n * DD + (lane << 2)] = o;
}

extern "C" void kernel_launch(void* const* d_in, const int* in_sizes, int n_in,
                              void* d_out, int out_size, void* d_ws, size_t ws_size,
                              hipStream_t stream) {
  (void)in_sizes; (void)n_in; (void)out_size; (void)ws_size;
  const float* X    = (const float*)d_in[0];
  const int*   edges= (const int*)d_in[1];
  const float* vt   = (const float*)d_in[2];
  const float* Wt   = (const float*)d_in[3];
  const float* bt   = (const float*)d_in[4];
  const float* th1  = (const float*)d_in[5];
  const float* b1   = (const float*)d_in[6];
  const float* aw1  = (const float*)d_in[7];
  const float* ab1  = (const float*)d_in[8];
  const float* th2  = (const float*)d_in[9];
  const float* b2   = (const float*)d_in[10];
  const float* aw2  = (const float*)d_in[11];
  const float* ab2  = (const float*)d_in[12];
  float* outp = (float*)d_out;

  // ---- workspace layout (R6 base + aE; q reuses cur) ----
  char* p = (char*)d_ws;
  float* P0  = (float*)p; p += (size_t)GN * DD * 4;
  float* P1  = (float*)p; p += (size_t)GN * DD * 4;
  float* w   = (float*)p; p += (size_t)GE * 4;
  float* dvis= (float*)p; p += (size_t)GN * 4;
  float* tn  = (float*)p; p += 16 * 4;
  int* cnt   = (int*)p;   p += (size_t)GN * 4;
  int* off   = (int*)p;   p += (size_t)(GN + 1) * 4;
  int* cur   = (int*)p;   p += (size_t)GN * 4;
  int* csr   = (int*)p;   p += (size_t)GE * GKK * 4;
  p = (char*)(((uintptr_t)p + 15) & ~(uintptr_t)15);
  double* dsum = (double*)p;
  unsigned int* mbits = (unsigned int*)(p + 8);
  p += 16;
  f16* BT1 = (f16*)p; p += (size_t)DD * DD * 2;
  f16* BT2 = (f16*)p; p += (size_t)DD * DD * 2;
  float* aE = (float*)p; p += (size_t)GE * 4;
  float* q  = (float*)cur;  // cur dead after k_fill

  f16* SA = (f16*)P0;
  f16* SB = (f16*)((char*)P0 + (size_t)GN * DD * 2);
  f16* SC = (f16*)P1;
  f16* SD = (f16*)((char*)P1 + (size_t)GN * DD * 2);

  hipMemsetAsync(cnt, 0, (size_t)GN * 4, stream);
  hipMemsetAsync(cur, 0, (size_t)GN * 4, stream);
  hipMemsetAsync(dsum, 0, 16, stream);

  k_reduce<<<196, 256, 0, stream>>>(vt, GE, mbits, dsum);
  k_w<<<196, 256, 0, stream>>>(vt, mbits, dsum, Wt, bt, w, tn);
  k_count<<<3125, 256, 0, stream>>>(edges, cnt);
  k_scan<<<1, 256, 0, stream>>>(cnt, off);
  k_fill<<<3125, 256, 0, stream>>>(edges, off, cur, csr);
  k_dv<<<196, 256, 0, stream>>>(off, csr, w, dvis);
  k_trans_h<<<64, 256, 0, stream>>>(th1, BT1);
  k_trans_h<<<64, 256, 0, stream>>>(th2, BT2);
  k_h0<<<12500, 256, 0, stream>>>(X, tn, SA);

  // ---- layer 1 ----
  k_gemm_mfma<<<782, 256, 0, stream>>>(SA, BT1, b1, dvis, SC);               // h0(A) -> g1(C)
  k_edge_msg<<<12500, 256, 0, stream>>>(SC, edges, w, SD);                   // g1 -> m1(D)
  k_node_smooth_q<<<12500, 256, 0, stream>>>(SD, off, csr, dvis, aw1, SB, q);// m1 -> s1(B) + q
  k_att<<<196, 256, 0, stream>>>(q, edges, ab1, aE);                         // q -> aE
  k_edge_msg<<<12500, 256, 0, stream>>>(SB, edges, aE, SC);                  // s1 -> m2(C; g1 dead)
  k_node_att_h<<<12500, 256, 0, stream>>>(SC, off, csr, cnt, SA);            // m2 -> L1(A; h0 dead)

  // ---- layer 2 ----
  k_gemm_mfma<<<782, 256, 0, stream>>>(SA, BT2, b2, dvis, SB);               // L1 -> g2(B; s1 dead)
  k_edge_msg<<<12500, 256, 0, stream>>>(SB, edges, w, SC);                   // g2 -> m3(C; m2 dead)
  k_node_smooth_q<<<12500, 256, 0, stream>>>(SC, off, csr, dvis, aw2, SD, q);// m3 -> s2(D) + q
  k_att<<<196, 256, 0, stream>>>(q, edges, ab2, aE);                         // q -> aE
  k_edge_msg<<<12500, 256, 0, stream>>>(SD, edges, aE, SC);                  // s2 -> m4(C; m3 dead)
  k_node_att_f<<<12500, 256, 0, stream>>>(SC, off, csr, cnt, outp);          // m4 -> out (f32)
}

// Round 11
// 746.278 us; speedup vs baseline: 1.4424x; 1.1786x over previous
//
#include <hip/hip_runtime.h>
#include <stdint.h>

#define GN 50000
#define GE 50000
#define GKK 16
#define DD 256
#define INDIM 240

typedef _Float16 f16;
typedef _Float16 half4 __attribute__((ext_vector_type(4)));
typedef _Float16 half8 __attribute__((ext_vector_type(8)));
typedef float f32x4 __attribute__((ext_vector_type(4)));

__device__ inline float4 ld_h4(const f16* p) {
  half4 v = *(const half4*)p;
  return make_float4((float)v.x, (float)v.y, (float)v.z, (float)v.w);
}
__device__ inline void st_h4c(f16* p, float4 v) {
  half4 h;
  h.x = (f16)fminf(fmaxf(v.x, -60000.f), 60000.f);
  h.y = (f16)fminf(fmaxf(v.y, -60000.f), 60000.f);
  h.z = (f16)fminf(fmaxf(v.z, -60000.f), 60000.f);
  h.w = (f16)fminf(fmaxf(v.w, -60000.f), 60000.f);
  *(half4*)p = h;
}
__device__ inline f16 h_clamp(float v) {
  return (f16)fminf(fmaxf(v, -60000.f), 60000.f);
}

// ---------- scalar reductions ----------
__global__ __launch_bounds__(256) void k_reduce(const float* __restrict__ t, int n,
                                                unsigned int* maxbits, double* sum) {
  int i0 = blockIdx.x * blockDim.x + threadIdx.x;
  int stride = gridDim.x * blockDim.x;
  float m = 0.f; double s = 0.0;
  for (int i = i0; i < n; i += stride) { float v = t[i]; m = fmaxf(m, v); s += (double)v; }
  for (int o = 32; o; o >>= 1) { m = fmaxf(m, __shfl_xor(m, o)); s += __shfl_xor(s, o); }
  if ((threadIdx.x & 63) == 0) { atomicMax(maxbits, __float_as_uint(m)); atomicAdd(sum, s); }
}

// ---------- w[e], tnode ----------
__global__ __launch_bounds__(256) void k_w(const float* __restrict__ t,
                                           const unsigned int* maxbits, const double* sum,
                                           const float* __restrict__ Wt, const float* __restrict__ bt,
                                           float* __restrict__ w, float* __restrict__ tn) {
  int i = blockIdx.x * blockDim.x + threadIdx.x;
  float maxt = __uint_as_float(*maxbits);
  if (i < GE) w[i] = expf((t[i] - maxt) * (1.0f / 365.0f));
  if (blockIdx.x == 0 && threadIdx.x < 16) {
    float mean = (float)(*sum / (double)GE);
    tn[threadIdx.x] = mean * Wt[threadIdx.x] + bt[threadIdx.x];
  }
}

// ---------- CSR build ----------
__global__ __launch_bounds__(256) void k_count(const int* __restrict__ edges, int* __restrict__ cnt) {
  int i = blockIdx.x * 256 + threadIdx.x;
  if (i < GE * GKK) atomicAdd(&cnt[edges[i]], 1);
}

__global__ __launch_bounds__(256) void k_scan(const int* __restrict__ cnt, int* __restrict__ off) {
  __shared__ int part[256];
  int t = threadIdx.x;
  const int chunk = (GN + 255) / 256;
  int beg = t * chunk, end = beg + chunk; if (end > GN) end = GN; if (beg > GN) beg = GN;
  int s = 0;
  for (int i = beg; i < end; i++) s += cnt[i];
  part[t] = s; __syncthreads();
  for (int d = 1; d < 256; d <<= 1) {
    int v = (t >= d) ? part[t - d] : 0;
    __syncthreads();
    part[t] += v;
    __syncthreads();
  }
  int base = (t == 0) ? 0 : part[t - 1];
  for (int i = beg; i < end; i++) { off[i] = base; base += cnt[i]; }
  if (t == 255) off[GN] = base;
}

__global__ __launch_bounds__(256) void k_fill(const int* __restrict__ edges, const int* __restrict__ off,
                                              int* __restrict__ cur, int* __restrict__ csr) {
  int i = blockIdx.x * 256 + threadIdx.x;
  if (i < GE * GKK) {
    int n = edges[i];
    int p = atomicAdd(&cur[n], 1);
    csr[off[n] + p] = i >> 4;  // edge id (K=16)
  }
}

// ---------- dv_isqrt ----------
__global__ __launch_bounds__(256) void k_dv(const int* __restrict__ off, const int* __restrict__ csr,
                                            const float* __restrict__ w, float* __restrict__ dvis) {
  int n = blockIdx.x * 256 + threadIdx.x;
  if (n >= GN) return;
  float dv = 0.f;
  int e0 = off[n], e1 = off[n + 1];
  for (int j = e0; j < e1; j++) dv += w[csr[j]];
  dvis[n] = dv > 0.f ? 1.0f / sqrtf(fmaxf(dv, 1e-12f)) : 0.f;
}

// ---------- h0 = concat(X, tnode) -> f16 ----------
__global__ __launch_bounds__(256) void k_h0(const float* __restrict__ X, const float* __restrict__ tn,
                                            f16* __restrict__ h) {
  int wid = threadIdx.x >> 6, lane = threadIdx.x & 63;
  int n = blockIdx.x * 4 + wid;
  if (n >= GN) return;
  float4 v;
  if (lane < 60) v = *(const float4*)&X[(size_t)n * INDIM + (lane << 2)];
  else           v = *(const float4*)&tn[(lane - 60) << 2];
  st_h4c(&h[(size_t)n * DD + (lane << 2)], v);
}

// ---------- W[k][n] f32 -> BT[n][k] f16 ----------
__global__ __launch_bounds__(256) void k_trans_h(const float* __restrict__ W, f16* __restrict__ BT) {
  __shared__ float tile[32][33];
  int bx = blockIdx.x & 7;
  int by = blockIdx.x >> 3;
  int tx = threadIdx.x & 31, ty = threadIdx.x >> 5;
#pragma unroll
  for (int i = 0; i < 4; i++) {
    int k = by * 32 + ty + i * 8;
    tile[ty + i * 8][tx] = W[(size_t)k * DD + bx * 32 + tx];
  }
  __syncthreads();
#pragma unroll
  for (int i = 0; i < 4; i++) {
    int n = bx * 32 + ty + i * 8;
    BT[(size_t)n * DD + by * 32 + tx] = (f16)tile[tx][ty + i * 8];
  }
}

// ---------- MFMA GEMM ----------
__global__ __launch_bounds__(256) void k_gemm_mfma(const f16* __restrict__ A,
                                                   const f16* __restrict__ BT,
                                                   const float* __restrict__ bias,
                                                   const float* __restrict__ dvis,
                                                   f16* __restrict__ out) {
  int t = threadIdx.x;
  int lane = t & 63;
  int wv = t >> 6;
  int row0 = blockIdx.x * 64;
  int col0 = wv * 64;
  int lr = lane & 15;
  int kg = lane >> 4;

  f32x4 acc[4][4];
#pragma unroll
  for (int m = 0; m < 4; m++)
#pragma unroll
    for (int n = 0; n < 4; n++) acc[m][n] = (f32x4)(0.f);

  for (int k0 = 0; k0 < DD; k0 += 32) {
    half8 a[4], b[4];
#pragma unroll
    for (int m = 0; m < 4; m++) {
      int r = row0 + m * 16 + lr;
      r = r < GN ? r : GN - 1;
      a[m] = *(const half8*)&A[(size_t)r * DD + k0 + kg * 8];
    }
#pragma unroll
    for (int n = 0; n < 4; n++) {
      int c = col0 + n * 16 + lr;
      b[n] = *(const half8*)&BT[(size_t)c * DD + k0 + kg * 8];
    }
#pragma unroll
    for (int m = 0; m < 4; m++)
#pragma unroll
      for (int n = 0; n < 4; n++)
        acc[m][n] = __builtin_amdgcn_mfma_f32_16x16x32_f16(a[m], b[n], acc[m][n], 0, 0, 0);
  }

#pragma unroll
  for (int m = 0; m < 4; m++) {
#pragma unroll
    for (int r = 0; r < 4; r++) {
      int row = row0 + m * 16 + kg * 4 + r;
      if (row < GN) {
        float s = dvis[row];
#pragma unroll
        for (int n = 0; n < 4; n++) {
          int c = col0 + n * 16 + lr;
          out[(size_t)row * DD + c] = h_clamp((acc[m][n][r] + bias[c]) * s);
        }
      }
    }
  }
}

// ---------- a[e] = sigmoid(mean_k q[edges[e,k]] + ab) ----------
__global__ __launch_bounds__(256) void k_att(const float* __restrict__ q, const int* __restrict__ edges,
                                             const float* __restrict__ ab, float* __restrict__ a) {
  int e = blockIdx.x * 256 + threadIdx.x;
  if (e >= GE) return;
  float s = 0.f;
#pragma unroll
  for (int k = 0; k < GKK; k++) s += q[edges[e * GKK + k]];
  a[e] = 1.0f / (1.0f + expf(-(s * (1.0f / GKK) + ab[0])));
}

// ---------- per-edge: msg[e] = scale[e]/16 * sum_k xs[edges[e,k]] ----------
__global__ __launch_bounds__(256) void k_edge_msg(const f16* __restrict__ xs, const int* __restrict__ edges,
                                                  const float* __restrict__ scale, f16* __restrict__ msg) {
  int wid = threadIdx.x >> 6, lane = threadIdx.x & 63;
  int e = blockIdx.x * 4 + wid;
  if (e >= GE) return;
  float4 s = make_float4(0.f, 0.f, 0.f, 0.f);
#pragma unroll
  for (int k = 0; k < GKK; k++) {
    int nd = edges[e * GKK + k];
    float4 v = ld_h4(&xs[(size_t)nd * DD + (lane << 2)]);
    s.x += v.x; s.y += v.y; s.z += v.z; s.w += v.w;
  }
  float f = scale[e] * (1.0f / GKK);
  s.x *= f; s.y *= f; s.z *= f; s.w *= f;
  st_h4c(&msg[(size_t)e * DD + (lane << 2)], s);
}

// ---------- 4-way batched node gather body: deepens MLP (4 indep row-loads in flight) ----------
__device__ inline float4 node_gather_sum(const f16* __restrict__ msg, const int* __restrict__ csr,
                                         int e0, int e1, int lane) {
  float4 s = make_float4(0.f, 0.f, 0.f, 0.f);
  int j = e0;
  for (; j + 4 <= e1; j += 4) {
    int ea = csr[j], eb = csr[j + 1], ec = csr[j + 2], ed = csr[j + 3];
    float4 va = ld_h4(&msg[(size_t)ea * DD + (lane << 2)]);
    float4 vb = ld_h4(&msg[(size_t)eb * DD + (lane << 2)]);
    float4 vc = ld_h4(&msg[(size_t)ec * DD + (lane << 2)]);
    float4 vd = ld_h4(&msg[(size_t)ed * DD + (lane << 2)]);
    s.x += va.x + vb.x + vc.x + vd.x;
    s.y += va.y + vb.y + vc.y + vd.y;
    s.z += va.z + vb.z + vc.z + vd.z;
    s.w += va.w + vb.w + vc.w + vd.w;
  }
  for (; j < e1; j++) {
    int e = csr[j];
    float4 v = ld_h4(&msg[(size_t)e * DD + (lane << 2)]);
    s.x += v.x; s.y += v.y; s.z += v.z; s.w += v.w;
  }
  return s;
}

// ---------- per-node smooth + fused rowdot ----------
__global__ __launch_bounds__(256) void k_node_smooth_q(const f16* __restrict__ msg, const int* __restrict__ off,
                                                       const int* __restrict__ csr, const float* __restrict__ dvis,
                                                       const float* __restrict__ aw,
                                                       f16* __restrict__ out, float* __restrict__ q) {
  int wid = threadIdx.x >> 6, lane = threadIdx.x & 63;
  int n = blockIdx.x * 4 + wid;
  if (n >= GN) return;
  float4 s = node_gather_sum(msg, csr, off[n], off[n + 1], lane);
  float sc = dvis[n];
  s.x *= sc; s.y *= sc; s.z *= sc; s.w *= sc;
  st_h4c(&out[(size_t)n * DD + (lane << 2)], s);
  float4 a4 = *(const float4*)&aw[lane << 2];
  float d = s.x * a4.x + s.y * a4.y + s.z * a4.z + s.w * a4.w;
  for (int o = 32; o; o >>= 1) d += __shfl_xor(d, o);
  if (lane == 0) q[n] = d;
}

// ---------- per-node attention aggregate, f16 out ----------
__global__ __launch_bounds__(256) void k_node_att_h(const f16* __restrict__ msg, const int* __restrict__ off,
                                                    const int* __restrict__ csr, const int* __restrict__ cnt,
                                                    f16* __restrict__ out) {
  int wid = threadIdx.x >> 6, lane = threadIdx.x & 63;
  int n = blockIdx.x * 4 + wid;
  if (n >= GN) return;
  float4 s = node_gather_sum(msg, csr, off[n], off[n + 1], lane);
  float inv = 1.0f / fmaxf((float)cnt[n], 1.0f);
  s.x *= inv; s.y *= inv; s.z *= inv; s.w *= inv;
  float4 o;
  o.x = s.x > 0.f ? s.x : 0.2f * s.x;
  o.y = s.y > 0.f ? s.y : 0.2f * s.y;
  o.z = s.z > 0.f ? s.z : 0.2f * s.z;
  o.w = s.w > 0.f ? s.w : 0.2f * s.w;
  st_h4c(&out[(size_t)n * DD + (lane << 2)], o);
}

// ---------- per-node attention aggregate, f32 out (final) ----------
__global__ __launch_bounds__(256) void k_node_att_f(const f16* __restrict__ msg, const int* __restrict__ off,
                                                    const int* __restrict__ csr, const int* __restrict__ cnt,
                                                    float* __restrict__ out) {
  int wid = threadIdx.x >> 6, lane = threadIdx.x & 63;
  int n = blockIdx.x * 4 + wid;
  if (n >= GN) return;
  float4 s = node_gather_sum(msg, csr, off[n], off[n + 1], lane);
  float inv = 1.0f / fmaxf((float)cnt[n], 1.0f);
  s.x *= inv; s.y *= inv; s.z *= inv; s.w *= inv;
  float4 o;
  o.x = s.x > 0.f ? s.x : 0.2f * s.x;
  o.y = s.y > 0.f ? s.y : 0.2f * s.y;
  o.z = s.z > 0.f ? s.z : 0.2f * s.z;
  o.w = s.w > 0.f ? s.w : 0.2f * s.w;
  *(float4*)&out[(size_t)n * DD + (lane << 2)] = o;
}

extern "C" void kernel_launch(void* const* d_in, const int* in_sizes, int n_in,
                              void* d_out, int out_size, void* d_ws, size_t ws_size,
                              hipStream_t stream) {
  (void)in_sizes; (void)n_in; (void)out_size; (void)ws_size;
  const float* X    = (const float*)d_in[0];
  const int*   edges= (const int*)d_in[1];
  const float* vt   = (const float*)d_in[2];
  const float* Wt   = (const float*)d_in[3];
  const float* bt   = (const float*)d_in[4];
  const float* th1  = (const float*)d_in[5];
  const float* b1   = (const float*)d_in[6];
  const float* aw1  = (const float*)d_in[7];
  const float* ab1  = (const float*)d_in[8];
  const float* th2  = (const float*)d_in[9];
  const float* b2   = (const float*)d_in[10];
  const float* aw2  = (const float*)d_in[11];
  const float* ab2  = (const float*)d_in[12];
  float* outp = (float*)d_out;

  char* p = (char*)d_ws;
  float* P0  = (float*)p; p += (size_t)GN * DD * 4;
  float* P1  = (float*)p; p += (size_t)GN * DD * 4;
  float* w   = (float*)p; p += (size_t)GE * 4;
  float* dvis= (float*)p; p += (size_t)GN * 4;
  float* tn  = (float*)p; p += 16 * 4;
  int* cnt   = (int*)p;   p += (size_t)GN * 4;
  int* off   = (int*)p;   p += (size_t)(GN + 1) * 4;
  int* cur   = (int*)p;   p += (size_t)GN * 4;
  int* csr   = (int*)p;   p += (size_t)GE * GKK * 4;
  p = (char*)(((uintptr_t)p + 15) & ~(uintptr_t)15);
  double* dsum = (double*)p;
  unsigned int* mbits = (unsigned int*)(p + 8);
  p += 16;
  f16* BT1 = (f16*)p; p += (size_t)DD * DD * 2;
  f16* BT2 = (f16*)p; p += (size_t)DD * DD * 2;
  float* aE = (float*)p; p += (size_t)GE * 4;
  float* q  = (float*)cur;  // cur dead after k_fill

  f16* SA = (f16*)P0;
  f16* SB = (f16*)((char*)P0 + (size_t)GN * DD * 2);
  f16* SC = (f16*)P1;
  f16* SD = (f16*)((char*)P1 + (size_t)GN * DD * 2);

  hipMemsetAsync(cnt, 0, (size_t)GN * 4, stream);
  hipMemsetAsync(cur, 0, (size_t)GN * 4, stream);
  hipMemsetAsync(dsum, 0, 16, stream);

  k_reduce<<<196, 256, 0, stream>>>(vt, GE, mbits, dsum);
  k_w<<<196, 256, 0, stream>>>(vt, mbits, dsum, Wt, bt, w, tn);
  k_count<<<3125, 256, 0, stream>>>(edges, cnt);
  k_scan<<<1, 256, 0, stream>>>(cnt, off);
  k_fill<<<3125, 256, 0, stream>>>(edges, off, cur, csr);
  k_dv<<<196, 256, 0, stream>>>(off, csr, w, dvis);
  k_trans_h<<<64, 256, 0, stream>>>(th1, BT1);
  k_trans_h<<<64, 256, 0, stream>>>(th2, BT2);
  k_h0<<<12500, 256, 0, stream>>>(X, tn, SA);

  // ---- layer 1 ----
  k_gemm_mfma<<<782, 256, 0, stream>>>(SA, BT1, b1, dvis, SC);               // h0(A) -> g1(C)
  k_edge_msg<<<12500, 256, 0, stream>>>(SC, edges, w, SD);                   // g1 -> m1(D)
  k_node_smooth_q<<<12500, 256, 0, stream>>>(SD, off, csr, dvis, aw1, SB, q);// m1 -> s1(B) + q
  k_att<<<196, 256, 0, stream>>>(q, edges, ab1, aE);                         // q -> aE
  k_edge_msg<<<12500, 256, 0, stream>>>(SB, edges, aE, SC);                  // s1 -> m2(C; g1 dead)
  k_node_att_h<<<12500, 256, 0, stream>>>(SC, off, csr, cnt, SA);            // m2 -> L1(A; h0 dead)

  // ---- layer 2 ----
  k_gemm_mfma<<<782, 256, 0, stream>>>(SA, BT2, b2, dvis, SB);               // L1 -> g2(B; s1 dead)
  k_edge_msg<<<12500, 256, 0, stream>>>(SB, edges, w, SC);                   // g2 -> m3(C; m2 dead)
  k_node_smooth_q<<<12500, 256, 0, stream>>>(SC, off, csr, dvis, aw2, SD, q);// m3 -> s2(D) + q
  k_att<<<196, 256, 0, stream>>>(q, edges, ab2, aE);                         // q -> aE
  k_edge_msg<<<12500, 256, 0, stream>>>(SD, edges, aE, SC);                  // s2 -> m4(C; m3 dead)
  k_node_att_f<<<12500, 256, 0, stream>>>(SC, off, csr, cnt, outp);          // m4 -> out (f32)
}

// Round 12
// 671.829 us; speedup vs baseline: 1.6023x; 1.1108x over previous
//
#include <hip/hip_runtime.h>
#include <stdint.h>

#define GN 50000
#define GE 50000
#define GKK 16
#define DD 256
#define INDIM 240
#define SCAN_BLOCKS 196

typedef _Float16 f16;
typedef _Float16 half4 __attribute__((ext_vector_type(4)));
typedef _Float16 half8 __attribute__((ext_vector_type(8)));
typedef float f32x4 __attribute__((ext_vector_type(4)));

__device__ inline float4 ld_h4(const f16* p) {
  half4 v = *(const half4*)p;
  return make_float4((float)v.x, (float)v.y, (float)v.z, (float)v.w);
}
__device__ inline void st_h4c(f16* p, float4 v) {
  half4 h;
  h.x = (f16)fminf(fmaxf(v.x, -60000.f), 60000.f);
  h.y = (f16)fminf(fmaxf(v.y, -60000.f), 60000.f);
  h.z = (f16)fminf(fmaxf(v.z, -60000.f), 60000.f);
  h.w = (f16)fminf(fmaxf(v.w, -60000.f), 60000.f);
  *(half4*)p = h;
}
__device__ inline f16 h_clamp(float v) {
  return (f16)fminf(fmaxf(v, -60000.f), 60000.f);
}

// ---------- scalar reductions ----------
__global__ __launch_bounds__(256) void k_reduce(const float* __restrict__ t, int n,
                                                unsigned int* maxbits, double* sum) {
  int i0 = blockIdx.x * blockDim.x + threadIdx.x;
  int stride = gridDim.x * blockDim.x;
  float m = 0.f; double s = 0.0;
  for (int i = i0; i < n; i += stride) { float v = t[i]; m = fmaxf(m, v); s += (double)v; }
  for (int o = 32; o; o >>= 1) { m = fmaxf(m, __shfl_xor(m, o)); s += __shfl_xor(s, o); }
  if ((threadIdx.x & 63) == 0) { atomicMax(maxbits, __float_as_uint(m)); atomicAdd(sum, s); }
}

// ---------- w[e], tnode ----------
__global__ __launch_bounds__(256) void k_w(const float* __restrict__ t,
                                           const unsigned int* maxbits, const double* sum,
                                           const float* __restrict__ Wt, const float* __restrict__ bt,
                                           float* __restrict__ w, float* __restrict__ tn) {
  int i = blockIdx.x * blockDim.x + threadIdx.x;
  float maxt = __uint_as_float(*maxbits);
  if (i < GE) w[i] = expf((t[i] - maxt) * (1.0f / 365.0f));
  if (blockIdx.x == 0 && threadIdx.x < 16) {
    float mean = (float)(*sum / (double)GE);
    tn[threadIdx.x] = mean * Wt[threadIdx.x] + bt[threadIdx.x];
  }
}

// ---------- CSR build ----------
__global__ __launch_bounds__(256) void k_count(const int* __restrict__ edges, int* __restrict__ cnt) {
  int i = blockIdx.x * 256 + threadIdx.x;
  if (i < GE * GKK) atomicAdd(&cnt[edges[i]], 1);
}

// ---- 3-phase parallel scan ----
__global__ __launch_bounds__(256) void k_scan1(const int* __restrict__ cnt, int* __restrict__ off,
                                               int* __restrict__ bsum) {
  __shared__ int sdata[256];
  int b = blockIdx.x, t = threadIdx.x;
  int i = b * 256 + t;
  int v = (i < GN) ? cnt[i] : 0;
  sdata[t] = v;
  __syncthreads();
  for (int d = 1; d < 256; d <<= 1) {
    int x = (t >= d) ? sdata[t - d] : 0;
    __syncthreads();
    sdata[t] += x;
    __syncthreads();
  }
  if (i < GN) off[i] = sdata[t] - v;          // local exclusive prefix
  if (t == 255) bsum[b] = sdata[255];
}

__global__ __launch_bounds__(256) void k_scan2(int* __restrict__ bsum) {
  __shared__ int s[256];
  int t = threadIdx.x;
  int v = (t < SCAN_BLOCKS) ? bsum[t] : 0;
  s[t] = v;
  __syncthreads();
  for (int d = 1; d < 256; d <<= 1) {
    int x = (t >= d) ? s[t - d] : 0;
    __syncthreads();
    s[t] += x;
    __syncthreads();
  }
  if (t < SCAN_BLOCKS) bsum[t] = s[t] - v;    // exclusive block base
}

__global__ __launch_bounds__(256) void k_scan3(int* __restrict__ off, const int* __restrict__ bsum) {
  int b = blockIdx.x, t = threadIdx.x;
  int i = b * 256 + t;
  if (i < GN) off[i] += bsum[b];
  if (i == 0) off[GN] = GE * GKK;             // total slots is a constant
}

__global__ __launch_bounds__(256) void k_fill(const int* __restrict__ edges, const int* __restrict__ off,
                                              int* __restrict__ cur, int* __restrict__ csr) {
  int i = blockIdx.x * 256 + threadIdx.x;
  if (i < GE * GKK) {
    int n = edges[i];
    int p = atomicAdd(&cur[n], 1);
    csr[off[n] + p] = i >> 4;  // edge id (K=16)
  }
}

// ---------- dv_isqrt ----------
__global__ __launch_bounds__(256) void k_dv(const int* __restrict__ off, const int* __restrict__ csr,
                                            const float* __restrict__ w, float* __restrict__ dvis) {
  int n = blockIdx.x * 256 + threadIdx.x;
  if (n >= GN) return;
  float dv = 0.f;
  int e0 = off[n], e1 = off[n + 1];
  for (int j = e0; j < e1; j++) dv += w[csr[j]];
  dvis[n] = dv > 0.f ? 1.0f / sqrtf(fmaxf(dv, 1e-12f)) : 0.f;
}

// ---------- h0 = concat(X, tnode) -> f16 ----------
__global__ __launch_bounds__(256) void k_h0(const float* __restrict__ X, const float* __restrict__ tn,
                                            f16* __restrict__ h) {
  int wid = threadIdx.x >> 6, lane = threadIdx.x & 63;
  int n = blockIdx.x * 4 + wid;
  if (n >= GN) return;
  float4 v;
  if (lane < 60) v = *(const float4*)&X[(size_t)n * INDIM + (lane << 2)];
  else           v = *(const float4*)&tn[(lane - 60) << 2];
  st_h4c(&h[(size_t)n * DD + (lane << 2)], v);
}

// ---------- W[k][n] f32 -> BT[n][k] f16 ----------
__global__ __launch_bounds__(256) void k_trans_h(const float* __restrict__ W, f16* __restrict__ BT) {
  __shared__ float tile[32][33];
  int bx = blockIdx.x & 7;
  int by = blockIdx.x >> 3;
  int tx = threadIdx.x & 31, ty = threadIdx.x >> 5;
#pragma unroll
  for (int i = 0; i < 4; i++) {
    int k = by * 32 + ty + i * 8;
    tile[ty + i * 8][tx] = W[(size_t)k * DD + bx * 32 + tx];
  }
  __syncthreads();
#pragma unroll
  for (int i = 0; i < 4; i++) {
    int n = bx * 32 + ty + i * 8;
    BT[(size_t)n * DD + by * 32 + tx] = (f16)tile[tx][ty + i * 8];
  }
}

// ---------- MFMA GEMM ----------
__global__ __launch_bounds__(256) void k_gemm_mfma(const f16* __restrict__ A,
                                                   const f16* __restrict__ BT,
                                                   const float* __restrict__ bias,
                                                   const float* __restrict__ dvis,
                                                   f16* __restrict__ out) {
  int t = threadIdx.x;
  int lane = t & 63;
  int wv = t >> 6;
  int row0 = blockIdx.x * 64;
  int col0 = wv * 64;
  int lr = lane & 15;
  int kg = lane >> 4;

  f32x4 acc[4][4];
#pragma unroll
  for (int m = 0; m < 4; m++)
#pragma unroll
    for (int n = 0; n < 4; n++) acc[m][n] = (f32x4)(0.f);

  for (int k0 = 0; k0 < DD; k0 += 32) {
    half8 a[4], b[4];
#pragma unroll
    for (int m = 0; m < 4; m++) {
      int r = row0 + m * 16 + lr;
      r = r < GN ? r : GN - 1;
      a[m] = *(const half8*)&A[(size_t)r * DD + k0 + kg * 8];
    }
#pragma unroll
    for (int n = 0; n < 4; n++) {
      int c = col0 + n * 16 + lr;
      b[n] = *(const half8*)&BT[(size_t)c * DD + k0 + kg * 8];
    }
#pragma unroll
    for (int m = 0; m < 4; m++)
#pragma unroll
      for (int n = 0; n < 4; n++)
        acc[m][n] = __builtin_amdgcn_mfma_f32_16x16x32_f16(a[m], b[n], acc[m][n], 0, 0, 0);
  }

#pragma unroll
  for (int m = 0; m < 4; m++) {
#pragma unroll
    for (int r = 0; r < 4; r++) {
      int row = row0 + m * 16 + kg * 4 + r;
      if (row < GN) {
        float s = dvis[row];
#pragma unroll
        for (int n = 0; n < 4; n++) {
          int c = col0 + n * 16 + lr;
          out[(size_t)row * DD + c] = h_clamp((acc[m][n][r] + bias[c]) * s);
        }
      }
    }
  }
}

// ---------- a[e] = sigmoid(mean_k q[edges[e,k]] + ab) ----------
__global__ __launch_bounds__(256) void k_att(const float* __restrict__ q, const int* __restrict__ edges,
                                             const float* __restrict__ ab, float* __restrict__ a) {
  int e = blockIdx.x * 256 + threadIdx.x;
  if (e >= GE) return;
  float s = 0.f;
#pragma unroll
  for (int k = 0; k < GKK; k++) s += q[edges[e * GKK + k]];
  a[e] = 1.0f / (1.0f + expf(-(s * (1.0f / GKK) + ab[0])));
}

// ---------- per-edge: msg[e] = scale[e]/16 * sum_k xs[edges[e,k]] ----------
__global__ __launch_bounds__(256) void k_edge_msg(const f16* __restrict__ xs, const int* __restrict__ edges,
                                                  const float* __restrict__ scale, f16* __restrict__ msg) {
  int wid = threadIdx.x >> 6, lane = threadIdx.x & 63;
  int e = blockIdx.x * 4 + wid;
  if (e >= GE) return;
  float4 s = make_float4(0.f, 0.f, 0.f, 0.f);
#pragma unroll
  for (int k = 0; k < GKK; k++) {
    int nd = edges[e * GKK + k];
    float4 v = ld_h4(&xs[(size_t)nd * DD + (lane << 2)]);
    s.x += v.x; s.y += v.y; s.z += v.z; s.w += v.w;
  }
  float f = scale[e] * (1.0f / GKK);
  s.x *= f; s.y *= f; s.z *= f; s.w *= f;
  st_h4c(&msg[(size_t)e * DD + (lane << 2)], s);
}

// ---------- 4-way batched node gather ----------
__device__ inline float4 node_gather_sum(const f16* __restrict__ msg, const int* __restrict__ csr,
                                         int e0, int e1, int lane) {
  float4 s = make_float4(0.f, 0.f, 0.f, 0.f);
  int j = e0;
  for (; j + 4 <= e1; j += 4) {
    int ea = csr[j], eb = csr[j + 1], ec = csr[j + 2], ed = csr[j + 3];
    float4 va = ld_h4(&msg[(size_t)ea * DD + (lane << 2)]);
    float4 vb = ld_h4(&msg[(size_t)eb * DD + (lane << 2)]);
    float4 vc = ld_h4(&msg[(size_t)ec * DD + (lane << 2)]);
    float4 vd = ld_h4(&msg[(size_t)ed * DD + (lane << 2)]);
    s.x += va.x + vb.x + vc.x + vd.x;
    s.y += va.y + vb.y + vc.y + vd.y;
    s.z += va.z + vb.z + vc.z + vd.z;
    s.w += va.w + vb.w + vc.w + vd.w;
  }
  for (; j < e1; j++) {
    int e = csr[j];
    float4 v = ld_h4(&msg[(size_t)e * DD + (lane << 2)]);
    s.x += v.x; s.y += v.y; s.z += v.z; s.w += v.w;
  }
  return s;
}

// ---------- per-node smooth + fused rowdot ----------
__global__ __launch_bounds__(256) void k_node_smooth_q(const f16* __restrict__ msg, const int* __restrict__ off,
                                                       const int* __restrict__ csr, const float* __restrict__ dvis,
                                                       const float* __restrict__ aw,
                                                       f16* __restrict__ out, float* __restrict__ q) {
  int wid = threadIdx.x >> 6, lane = threadIdx.x & 63;
  int n = blockIdx.x * 4 + wid;
  if (n >= GN) return;
  float4 s = node_gather_sum(msg, csr, off[n], off[n + 1], lane);
  float sc = dvis[n];
  s.x *= sc; s.y *= sc; s.z *= sc; s.w *= sc;
  st_h4c(&out[(size_t)n * DD + (lane << 2)], s);
  float4 a4 = *(const float4*)&aw[lane << 2];
  float d = s.x * a4.x + s.y * a4.y + s.z * a4.z + s.w * a4.w;
  for (int o = 32; o; o >>= 1) d += __shfl_xor(d, o);
  if (lane == 0) q[n] = d;
}

// ---------- per-node attention aggregate, f16 out ----------
__global__ __launch_bounds__(256) void k_node_att_h(const f16* __restrict__ msg, const int* __restrict__ off,
                                                    const int* __restrict__ csr, const int* __restrict__ cnt,
                                                    f16* __restrict__ out) {
  int wid = threadIdx.x >> 6, lane = threadIdx.x & 63;
  int n = blockIdx.x * 4 + wid;
  if (n >= GN) return;
  float4 s = node_gather_sum(msg, csr, off[n], off[n + 1], lane);
  float inv = 1.0f / fmaxf((float)cnt[n], 1.0f);
  s.x *= inv; s.y *= inv; s.z *= inv; s.w *= inv;
  float4 o;
  o.x = s.x > 0.f ? s.x : 0.2f * s.x;
  o.y = s.y > 0.f ? s.y : 0.2f * s.y;
  o.z = s.z > 0.f ? s.z : 0.2f * s.z;
  o.w = s.w > 0.f ? s.w : 0.2f * s.w;
  st_h4c(&out[(size_t)n * DD + (lane << 2)], o);
}

// ---------- per-node attention aggregate, f32 out (final) ----------
__global__ __launch_bounds__(256) void k_node_att_f(const f16* __restrict__ msg, const int* __restrict__ off,
                                                    const int* __restrict__ csr, const int* __restrict__ cnt,
                                                    float* __restrict__ out) {
  int wid = threadIdx.x >> 6, lane = threadIdx.x & 63;
  int n = blockIdx.x * 4 + wid;
  if (n >= GN) return;
  float4 s = node_gather_sum(msg, csr, off[n], off[n + 1], lane);
  float inv = 1.0f / fmaxf((float)cnt[n], 1.0f);
  s.x *= inv; s.y *= inv; s.z *= inv; s.w *= inv;
  float4 o;
  o.x = s.x > 0.f ? s.x : 0.2f * s.x;
  o.y = s.y > 0.f ? s.y : 0.2f * s.y;
  o.z = s.z > 0.f ? s.z : 0.2f * s.z;
  o.w = s.w > 0.f ? s.w : 0.2f * s.w;
  *(float4*)&out[(size_t)n * DD + (lane << 2)] = o;
}

extern "C" void kernel_launch(void* const* d_in, const int* in_sizes, int n_in,
                              void* d_out, int out_size, void* d_ws, size_t ws_size,
                              hipStream_t stream) {
  (void)in_sizes; (void)n_in; (void)out_size; (void)ws_size;
  const float* X    = (const float*)d_in[0];
  const int*   edges= (const int*)d_in[1];
  const float* vt   = (const float*)d_in[2];
  const float* Wt   = (const float*)d_in[3];
  const float* bt   = (const float*)d_in[4];
  const float* th1  = (const float*)d_in[5];
  const float* b1   = (const float*)d_in[6];
  const float* aw1  = (const float*)d_in[7];
  const float* ab1  = (const float*)d_in[8];
  const float* th2  = (const float*)d_in[9];
  const float* b2   = (const float*)d_in[10];
  const float* aw2  = (const float*)d_in[11];
  const float* ab2  = (const float*)d_in[12];
  float* outp = (float*)d_out;

  char* p = (char*)d_ws;
  float* P0  = (float*)p; p += (size_t)GN * DD * 4;
  float* P1  = (float*)p; p += (size_t)GN * DD * 4;
  float* w   = (float*)p; p += (size_t)GE * 4;
  float* dvis= (float*)p; p += (size_t)GN * 4;
  float* tn  = (float*)p; p += 16 * 4;
  int* cnt   = (int*)p;   p += (size_t)GN * 4;
  int* off   = (int*)p;   p += (size_t)(GN + 1) * 4;
  int* cur   = (int*)p;   p += (size_t)GN * 4;
  int* csr   = (int*)p;   p += (size_t)GE * GKK * 4;
  p = (char*)(((uintptr_t)p + 15) & ~(uintptr_t)15);
  double* dsum = (double*)p;
  unsigned int* mbits = (unsigned int*)(p + 8);
  p += 16;
  f16* BT1 = (f16*)p; p += (size_t)DD * DD * 2;
  f16* BT2 = (f16*)p; p += (size_t)DD * DD * 2;
  float* aE = (float*)p; p += (size_t)GE * 4;
  int* bsum = (int*)p; p += 256 * 4;
  float* q  = (float*)cur;  // cur dead after k_fill

  f16* SA = (f16*)P0;
  f16* SB = (f16*)((char*)P0 + (size_t)GN * DD * 2);
  f16* SC = (f16*)P1;
  f16* SD = (f16*)((char*)P1 + (size_t)GN * DD * 2);

  hipMemsetAsync(cnt, 0, (size_t)GN * 4, stream);
  hipMemsetAsync(cur, 0, (size_t)GN * 4, stream);
  hipMemsetAsync(dsum, 0, 16, stream);

  k_reduce<<<196, 256, 0, stream>>>(vt, GE, mbits, dsum);
  k_w<<<196, 256, 0, stream>>>(vt, mbits, dsum, Wt, bt, w, tn);
  k_count<<<3125, 256, 0, stream>>>(edges, cnt);
  k_scan1<<<SCAN_BLOCKS, 256, 0, stream>>>(cnt, off, bsum);
  k_scan2<<<1, 256, 0, stream>>>(bsum);
  k_scan3<<<SCAN_BLOCKS, 256, 0, stream>>>(off, bsum);
  k_fill<<<3125, 256, 0, stream>>>(edges, off, cur, csr);
  k_dv<<<196, 256, 0, stream>>>(off, csr, w, dvis);
  k_trans_h<<<64, 256, 0, stream>>>(th1, BT1);
  k_trans_h<<<64, 256, 0, stream>>>(th2, BT2);
  k_h0<<<12500, 256, 0, stream>>>(X, tn, SA);

  // ---- layer 1 ----
  k_gemm_mfma<<<782, 256, 0, stream>>>(SA, BT1, b1, dvis, SC);               // h0(A) -> g1(C)
  k_edge_msg<<<12500, 256, 0, stream>>>(SC, edges, w, SD);                   // g1 -> m1(D)
  k_node_smooth_q<<<12500, 256, 0, stream>>>(SD, off, csr, dvis, aw1, SB, q);// m1 -> s1(B) + q
  k_att<<<196, 256, 0, stream>>>(q, edges, ab1, aE);                         // q -> aE
  k_edge_msg<<<12500, 256, 0, stream>>>(SB, edges, aE, SC);                  // s1 -> m2(C; g1 dead)
  k_node_att_h<<<12500, 256, 0, stream>>>(SC, off, csr, cnt, SA);            // m2 -> L1(A; h0 dead)

  // ---- layer 2 ----
  k_gemm_mfma<<<782, 256, 0, stream>>>(SA, BT2, b2, dvis, SB);               // L1 -> g2(B; s1 dead)
  k_edge_msg<<<12500, 256, 0, stream>>>(SB, edges, w, SC);                   // g2 -> m3(C; m2 dead)
  k_node_smooth_q<<<12500, 256, 0, stream>>>(SC, off, csr, dvis, aw2, SD, q);// m3 -> s2(D) + q
  k_att<<<196, 256, 0, stream>>>(q, edges, ab2, aE);                         // q -> aE
  k_edge_msg<<<12500, 256, 0, stream>>>(SD, edges, aE, SC);                  // s2 -> m4(C; m3 dead)
  k_node_att_f<<<12500, 256, 0, stream>>>(SC, off, csr, cnt, outp);          // m4 -> out (f32)
}